// Round 14
// baseline (112.238 us; speedup 1.0000x reference)
//
#include <hip/hip_runtime.h>
#include <math.h>

#define NP 128       // patches per side
#define NB 32        // batch (light dirs)

typedef float vf4 __attribute__((ext_vector_type(4)));  // native 16B vector

// ---------------------------------------------------------------------------
// R13 structure, PLAIN stores (single-variable A/B vs R13's NT):
//  phase 1: threads 0..127 run the MLP for patch (ph, t), 3 f32 colors -> LDS.
//  phase 2: thread t owns chunks {t, t+256, t+512} of the 768-chunk row
//           pattern; computes the 3 float4 values once, stores each 8x.
//           Per-wave address sequence strictly monotonic (as R10/R13).
// ---------------------------------------------------------------------------
__global__ __launch_bounds__(256) void fused_relight(
    const float* __restrict__ ld,   // [32][2]
    const float* __restrict__ w1,   // [p][8][2]
    const float* __restrict__ b1,   // [p][8]
    const float* __restrict__ w2,   // [p][8][8]
    const float* __restrict__ b2,   // [p][8]
    const float* __restrict__ w3,   // [p][8][8]
    const float* __restrict__ b3,   // [p][8]
    const float* __restrict__ wo,   // [p][3][8]
    const float* __restrict__ bo,   // [p][3]
    float* __restrict__ out)        // [32][1024][1024][3] f32
{
    int bid = blockIdx.x;        // 0 .. 4095
    int ph = bid >> 5;           // patch row
    int b  = bid & 31;           // light index
    int t  = threadIdx.x;        // 0 .. 255

    __shared__ float cl[NP * 3];  // 384 floats

    if (t < NP) {
        int p = ph * NP + t;     // patch id
        float x0 = ld[2 * b + 0];
        float x1 = ld[2 * b + 1];

        float h[8], g[8];
        {   // layer 1: 2 -> 8
            const float* W  = w1 + (size_t)p * 16;
            const float* Bv = b1 + (size_t)p * 8;
#pragma unroll
            for (int o = 0; o < 8; ++o) {
                float s = fmaf(W[2 * o + 0], x0, fmaf(W[2 * o + 1], x1, Bv[o]));
                h[o] = fmaxf(0.f, s);
            }
        }
        {   // layer 2: 8 -> 8
            const float* W  = w2 + (size_t)p * 64;
            const float* Bv = b2 + (size_t)p * 8;
#pragma unroll
            for (int o = 0; o < 8; ++o) {
                float s = Bv[o];
#pragma unroll
                for (int i = 0; i < 8; ++i) s = fmaf(W[8 * o + i], h[i], s);
                g[o] = fmaxf(0.f, s);
            }
        }
        {   // layer 3: 8 -> 8
            const float* W  = w3 + (size_t)p * 64;
            const float* Bv = b3 + (size_t)p * 8;
#pragma unroll
            for (int o = 0; o < 8; ++o) {
                float s = Bv[o];
#pragma unroll
                for (int i = 0; i < 8; ++i) s = fmaf(W[8 * o + i], g[i], s);
                h[o] = fmaxf(0.f, s);
            }
        }
        {   // out layer: 8 -> 3, sigmoid -> LDS
            const float* W  = wo + (size_t)p * 24;
            const float* Bv = bo + (size_t)p * 3;
#pragma unroll
            for (int c = 0; c < 3; ++c) {
                float s = Bv[c];
#pragma unroll
                for (int i = 0; i < 8; ++i) s = fmaf(W[8 * c + i], h[i], s);
                cl[t * 3 + c] = 1.f / (1.f + expf(-s));
            }
        }
    }
    __syncthreads();

    // Phase 2: compute this thread's 3 chunk values once.
    vf4 v[3];
#pragma unroll
    for (int j = 0; j < 3; ++j) {
        int ct = j * 256 + t;         // 0..767
        int pw = ct / 6;
        int s  = ct % 3;

        float c0 = cl[pw * 3 + 0];
        float c1 = cl[pw * 3 + 1];
        float c2 = cl[pw * 3 + 2];
        float ca = (s == 0) ? c0 : ((s == 1) ? c1 : c2);
        float cb = (s == 0) ? c1 : ((s == 1) ? c2 : c0);
        float cc = (s == 0) ? c2 : ((s == 1) ? c0 : c1);

        v[j].x = ca; v[j].y = cb; v[j].z = cc; v[j].w = ca;
    }

    // Same monotonic per-wave address sequence; plain stores.
    vf4* op = (vf4*)out + (size_t)b * 786432 + (size_t)ph * 6144;
#pragma unroll
    for (int row = 0; row < 8; ++row) {
        op[row * 768 + t]       = v[0];
        op[row * 768 + 256 + t] = v[1];
        op[row * 768 + 512 + t] = v[2];
    }
}

extern "C" void kernel_launch(void* const* d_in, const int* in_sizes, int n_in,
                              void* d_out, int out_size, void* d_ws, size_t ws_size,
                              hipStream_t stream) {
    const float* ld = (const float*)d_in[0];
    const float* w1 = (const float*)d_in[1];
    const float* b1 = (const float*)d_in[2];
    const float* w2 = (const float*)d_in[3];
    const float* b2 = (const float*)d_in[4];
    const float* w3 = (const float*)d_in[5];
    const float* b3 = (const float*)d_in[6];
    const float* wo = (const float*)d_in[7];
    const float* bo = (const float*)d_in[8];

    float* out = (float*)d_out;

    fused_relight<<<dim3(NP * NB), dim3(256), 0, stream>>>(
        ld, w1, b1, w2, b2, w3, b3, wo, bo, out);
}

// Round 15
// 88.183 us; speedup vs baseline: 1.2728x; 1.2728x over previous
//
#include <hip/hip_runtime.h>
#include <math.h>

#define NP 128       // patches per side
#define NB 32        // batch (light dirs)

typedef float vf4 __attribute__((ext_vector_type(4)));  // native 16B vector

// ---------------------------------------------------------------------------
// R13 structure (NT stores, hoisted v[3]), block mapping b-major:
//   bid = b*128 + ph  ->  xcd = bid%8 = ph%8 : all 32 blocks sharing row ph's
//   weights run on ONE XCD; per-XCD weight share (1.4 MB) fits L2 -> weights
//   fetched from HBM once instead of 8x.
// ---------------------------------------------------------------------------
__global__ __launch_bounds__(256) void fused_relight(
    const float* __restrict__ ld,   // [32][2]
    const float* __restrict__ w1,   // [p][8][2]
    const float* __restrict__ b1,   // [p][8]
    const float* __restrict__ w2,   // [p][8][8]
    const float* __restrict__ b2,   // [p][8]
    const float* __restrict__ w3,   // [p][8][8]
    const float* __restrict__ b3,   // [p][8]
    const float* __restrict__ wo,   // [p][3][8]
    const float* __restrict__ bo,   // [p][3]
    float* __restrict__ out)        // [32][1024][1024][3] f32
{
    int bid = blockIdx.x;        // 0 .. 4095
    int b  = bid >> 7;           // light index   (b-major)
    int ph = bid & 127;          // patch row -> xcd = ph % 8
    int t  = threadIdx.x;        // 0 .. 255

    __shared__ float cl[NP * 3];  // 384 floats

    if (t < NP) {
        int p = ph * NP + t;     // patch id
        float x0 = ld[2 * b + 0];
        float x1 = ld[2 * b + 1];

        float h[8], g[8];
        {   // layer 1: 2 -> 8
            const float* W  = w1 + (size_t)p * 16;
            const float* Bv = b1 + (size_t)p * 8;
#pragma unroll
            for (int o = 0; o < 8; ++o) {
                float s = fmaf(W[2 * o + 0], x0, fmaf(W[2 * o + 1], x1, Bv[o]));
                h[o] = fmaxf(0.f, s);
            }
        }
        {   // layer 2: 8 -> 8
            const float* W  = w2 + (size_t)p * 64;
            const float* Bv = b2 + (size_t)p * 8;
#pragma unroll
            for (int o = 0; o < 8; ++o) {
                float s = Bv[o];
#pragma unroll
                for (int i = 0; i < 8; ++i) s = fmaf(W[8 * o + i], h[i], s);
                g[o] = fmaxf(0.f, s);
            }
        }
        {   // layer 3: 8 -> 8
            const float* W  = w3 + (size_t)p * 64;
            const float* Bv = b3 + (size_t)p * 8;
#pragma unroll
            for (int o = 0; o < 8; ++o) {
                float s = Bv[o];
#pragma unroll
                for (int i = 0; i < 8; ++i) s = fmaf(W[8 * o + i], g[i], s);
                h[o] = fmaxf(0.f, s);
            }
        }
        {   // out layer: 8 -> 3, sigmoid -> LDS
            const float* W  = wo + (size_t)p * 24;
            const float* Bv = bo + (size_t)p * 3;
#pragma unroll
            for (int c = 0; c < 3; ++c) {
                float s = Bv[c];
#pragma unroll
                for (int i = 0; i < 8; ++i) s = fmaf(W[8 * c + i], h[i], s);
                cl[t * 3 + c] = 1.f / (1.f + expf(-s));
            }
        }
    }
    __syncthreads();

    // Phase 2: compute this thread's 3 chunk values once.
    // Chunk ct (0..767): patch pw = ct/6, start channel s = ct%3,
    // value = [s, s+1, s+2, s] (mod 3) of that patch's color.
    vf4 v[3];
#pragma unroll
    for (int j = 0; j < 3; ++j) {
        int ct = j * 256 + t;         // 0..767
        int pw = ct / 6;
        int s  = ct % 3;

        float c0 = cl[pw * 3 + 0];
        float c1 = cl[pw * 3 + 1];
        float c2 = cl[pw * 3 + 2];
        float ca = (s == 0) ? c0 : ((s == 1) ? c1 : c2);
        float cb = (s == 0) ? c1 : ((s == 1) ? c2 : c0);
        float cc = (s == 0) ? c2 : ((s == 1) ? c0 : c1);

        v[j].x = ca; v[j].y = cb; v[j].z = cc; v[j].w = ca;
    }

    // NT stores, same per-wave address sequence as R13.
    vf4* op = (vf4*)out + (size_t)b * 786432 + (size_t)ph * 6144;
#pragma unroll
    for (int row = 0; row < 8; ++row) {
        __builtin_nontemporal_store(v[0], &op[row * 768 + t]);
        __builtin_nontemporal_store(v[1], &op[row * 768 + 256 + t]);
        __builtin_nontemporal_store(v[2], &op[row * 768 + 512 + t]);
    }
}

extern "C" void kernel_launch(void* const* d_in, const int* in_sizes, int n_in,
                              void* d_out, int out_size, void* d_ws, size_t ws_size,
                              hipStream_t stream) {
    const float* ld = (const float*)d_in[0];
    const float* w1 = (const float*)d_in[1];
    const float* b1 = (const float*)d_in[2];
    const float* w2 = (const float*)d_in[3];
    const float* b2 = (const float*)d_in[4];
    const float* w3 = (const float*)d_in[5];
    const float* b3 = (const float*)d_in[6];
    const float* wo = (const float*)d_in[7];
    const float* bo = (const float*)d_in[8];

    float* out = (float*)d_out;

    fused_relight<<<dim3(NB * NP), dim3(256), 0, stream>>>(
        ld, w1, b1, w2, b2, w3, b3, wo, bo, out);
}